// Round 4
// baseline (239.221 us; speedup 1.0000x reference)
//
#include <hip/hip_runtime.h>
#include <hip/hip_bf16.h>
#include <hip/hip_cooperative_groups.h>

namespace cg = cooperative_groups;

#define LEVEL 256
#define BLOCKS 8
// B=16, H=W=1024, bm=bn=128, tv = 16384/256*10 = 640

// ---------------------------------------------------------------------------
// Fused cooperative CLAHE. grid = 512 workgroups x 256 threads; each workgroup
// owns TWO 128x128 image blocks (pixels cached in 32 packed-u8 VGPRs).
// Phase A: histogram + clip + scan -> map to global. Grid sync. Phase B:
// 4 quadrant tables, corners packed u8x4 in u32 (single ds_read_b32/pixel),
// blend, store. __launch_bounds__(256,4) caps VGPR at 128 -> occupancy
// ceiling 4 blocks/CU -> 1024 co-resident >= 512 launched (2x margin vs the
// round-3 exact-fit launch that failed).
// ---------------------------------------------------------------------------
__global__ __launch_bounds__(256, 4) void clahe_fused(const float* __restrict__ img,
                                                      float* __restrict__ out,
                                                      float* __restrict__ maps) {
#pragma clang fp contract(off)
    __shared__ int   hist[256];
    __shared__ float red[256];
    __shared__ float scan[256];
    __shared__ float s_me;
    __shared__ unsigned int tbl[4][256];   // per-quadrant packed {lu,lb,ru,rb}

    const int t = threadIdx.x;
    unsigned int pix[2][16];

    // ---- Phase A: histogram + clip + scan for both image blocks ----
    for (int g = 0; g < 2; ++g) {
        const int bid = blockIdx.x * 2 + g;    // 0..1023
        const int b   = bid >> 6;
        const int blk = bid & 63;
        const int br  = blk >> 3;
        const int bc  = blk & 7;

        hist[t] = 0;
        __syncthreads();

        const size_t base = (size_t)b * 1048576 + (size_t)(br * 128) * 1024 + (size_t)(bc * 128);
        const float* p = img + base;
#pragma unroll
        for (int it = 0; it < 16; ++it) {
            int idx = it * 256 + t;            // 0..4095
            int y   = idx >> 5;                // 0..127
            int x   = (idx & 31) * 4;          // 0..124
            float4 v = *(const float4*)(p + (size_t)y * 1024 + x);
            int va = (int)v.x, vb = (int)v.y, vc = (int)v.z, vd = (int)v.w;
            atomicAdd(&hist[va], 1);
            atomicAdd(&hist[vb], 1);
            atomicAdd(&hist[vc], 1);
            atomicAdd(&hist[vd], 1);
            pix[g][it] = (unsigned)va | ((unsigned)vb << 8) |
                         ((unsigned)vc << 16) | ((unsigned)vd << 24);
        }
        __syncthreads();

        // clip: tv=640, redistribute excess uniformly (integer-exact in fp32)
        const float tv = 640.0f;
        float h = (float)hist[t];
        red[t] = fmaxf(h - tv, 0.0f);
        __syncthreads();
        for (int off = 128; off > 0; off >>= 1) {
            if (t < off) red[t] += red[t + off];
            __syncthreads();
        }
        if (t == 0) s_me = red[0] * (1.0f / 256.0f);   // exact /2^8
        __syncthreads();
        const float me = s_me;
        float clip = floorf(((h >= tv) ? tv : h) + me);

        // inclusive scan over 256 bins (integer-valued -> exact any order)
        scan[t] = clip;
        __syncthreads();
        for (int off = 1; off < 256; off <<= 1) {
            float add = (t >= off) ? scan[t - off] : 0.0f;
            __syncthreads();
            scan[t] += add;
            __syncthreads();
        }
        float cdf = scan[t] * (255.0f / 16384.0f);     // exact 255/2^14
        maps[(size_t)bid * 256 + t] = (float)(((int)floorf(cdf)) & 255);
        __syncthreads();
    }

    // ---- publish maps, grid-wide sync ----
    __threadfence();
    cg::this_grid().sync();

    // ---- Phase B: quadrant tables + blend + store, per image block ----
    for (int g = 0; g < 2; ++g) {
        const int bid = blockIdx.x * 2 + g;
        const int b   = bid >> 6;
        const int blk = bid & 63;
        const int br  = blk >> 3;
        const int bc  = blk & 7;
        const float* mb = maps + (size_t)b * 64 * 256;

        __syncthreads();   // previous g's tbl reads complete
#pragma unroll
        for (int q = 0; q < 4; ++q) {
            int qi = q >> 1, qj = q & 1;
            int i0 = br * 128 + qi * 64;
            int j0 = bc * 128 + qj * 64;
            int r  = (i0 >= 64) ? ((i0 - 64) >> 7) : 0;
            int c  = (j0 >= 64) ? ((j0 - 64) >> 7) : 0;
            int rp = min(r + 1, BLOCKS - 1);
            int cp = min(c + 1, BLOCKS - 1);
            unsigned lu = (unsigned)(int)mb[(r  * 8 + c ) * 256 + t];
            unsigned lb = (unsigned)(int)mb[(rp * 8 + c ) * 256 + t];
            unsigned ru = (unsigned)(int)mb[(r  * 8 + cp) * 256 + t];
            unsigned rb = (unsigned)(int)mb[(rp * 8 + cp) * 256 + t];
            tbl[q][t] = lu | (lb << 8) | (ru << 16) | (rb << 24);
        }
        __syncthreads();

        const size_t base = (size_t)b * 1048576 + (size_t)(br * 128) * 1024 + (size_t)(bc * 128);
        float* po = out + base;
#pragma unroll
        for (int it = 0; it < 16; ++it) {
            int idx = it * 256 + t;
            int y   = idx >> 5;
            int x   = (idx & 31) * 4;
            int i   = br * 128 + y;
            int q   = ((y >> 6) << 1) | (x >> 6);

            int   r  = (i >= 64) ? ((i - 64) >> 7) : 0;
            float x1 = (r >= BLOCKS - 1) ? 0.0f : (float)(i - (r * 128 + 64)) * 0.0078125f;
            float x0 = 1.0f - x1;

            unsigned w = pix[g][it];
            float4 o4;
            float* ov = (float*)&o4;
#pragma unroll
            for (int k = 0; k < 4; ++k) {
                int jj = bc * 128 + x + k;
                int cc = (jj >= 64) ? ((jj - 64) >> 7) : 0;
                float y1 = (cc >= BLOCKS - 1) ? 0.0f : (float)(jj - (cc * 128 + 64)) * 0.0078125f;
                unsigned mv = tbl[q][(w >> (k * 8)) & 255u];
                float lu = (float)(mv & 255u);
                float lb = (float)((mv >> 8) & 255u);
                float ru = (float)((mv >> 16) & 255u);
                float rb = (float)(mv >> 24);
                // exact expression order of the reference; no FMA contraction
                float o = (1.0f - y1) * (x0 * lu + x1 * lb)
                        + y1 * (x0 * ru + x1 * rb);
                ov[k] = (float)(((int)o) & 255);   // trunc then floor-mod 256
            }
            *(float4*)(po + (size_t)y * 1024 + x) = o4;
        }
    }
}

// ---------------------------------------------------------------------------
// Fallback path (round-2 structure): hist kernel + map kernel via u8 staging.
// ---------------------------------------------------------------------------
__global__ __launch_bounds__(256) void clahe_hist_kernel(const float* __restrict__ img,
                                                         float* __restrict__ maps,
                                                         unsigned char* __restrict__ u8img) {
    __shared__ int   hist[256];
    __shared__ float red[256];
    __shared__ float scan[256];
    __shared__ float s_me;

    const int t   = threadIdx.x;
    const int bid = blockIdx.x;
    const int b   = bid >> 6;
    const int blk = bid & 63;
    const int br  = blk >> 3;
    const int bc  = blk & 7;

    hist[t] = 0;
    __syncthreads();

    const size_t base = (size_t)b * 1048576 + (size_t)(br * 128) * 1024 + (size_t)(bc * 128);
    const float* p = img + base;
    unsigned char* q8 = u8img ? (u8img + base) : nullptr;
    for (int it = 0; it < 16; ++it) {
        int idx = it * 256 + t;
        int y   = idx >> 5;
        int x   = (idx & 31) * 4;
        float4 v = *(const float4*)(p + (size_t)y * 1024 + x);
        int va = (int)v.x, vb = (int)v.y, vc = (int)v.z, vd = (int)v.w;
        atomicAdd(&hist[va], 1);
        atomicAdd(&hist[vb], 1);
        atomicAdd(&hist[vc], 1);
        atomicAdd(&hist[vd], 1);
        if (q8) {
            uchar4 pk;
            pk.x = (unsigned char)va; pk.y = (unsigned char)vb;
            pk.z = (unsigned char)vc; pk.w = (unsigned char)vd;
            *(uchar4*)(q8 + (size_t)y * 1024 + x) = pk;
        }
    }
    __syncthreads();

    const float tv = 640.0f;
    float h = (float)hist[t];
    red[t] = fmaxf(h - tv, 0.0f);
    __syncthreads();
    for (int off = 128; off > 0; off >>= 1) {
        if (t < off) red[t] += red[t + off];
        __syncthreads();
    }
    if (t == 0) s_me = red[0] * (1.0f / 256.0f);
    __syncthreads();
    const float me = s_me;
    float clip = floorf(((h >= tv) ? tv : h) + me);

    scan[t] = clip;
    __syncthreads();
    for (int off = 1; off < 256; off <<= 1) {
        float add = (t >= off) ? scan[t - off] : 0.0f;
        __syncthreads();
        scan[t] += add;
        __syncthreads();
    }
    float cdf = scan[t] * (255.0f / 16384.0f);
    maps[(size_t)bid * 256 + t] = (float)(((int)floorf(cdf)) & 255);
}

template <bool U8>
__global__ __launch_bounds__(256) void clahe_map_kernel(const float* __restrict__ imgf,
                                                        const unsigned char* __restrict__ img8,
                                                        const float* __restrict__ maps,
                                                        float* __restrict__ out) {
#pragma clang fp contract(off)
    __shared__ unsigned int tbl[256];   // packed {lu,lb,ru,rb} u8x4

    const int t  = threadIdx.x;
    const int b  = blockIdx.z;
    const int i0 = blockIdx.y * 64;
    const int j0 = blockIdx.x * 64;

    const int r  = (i0 >= 64) ? ((i0 - 64) >> 7) : 0;
    const int c  = (j0 >= 64) ? ((j0 - 64) >> 7) : 0;
    const int rp = min(r + 1, BLOCKS - 1);
    const int cp = min(c + 1, BLOCKS - 1);
    const bool rEdge = (r >= BLOCKS - 1);
    const bool cEdge = (c >= BLOCKS - 1);

    const float* mb = maps + (size_t)b * 64 * 256;
    {
        unsigned lu = (unsigned)(int)mb[(r  * 8 + c ) * 256 + t];
        unsigned lb = (unsigned)(int)mb[(rp * 8 + c ) * 256 + t];
        unsigned ru = (unsigned)(int)mb[(r  * 8 + cp) * 256 + t];
        unsigned rb = (unsigned)(int)mb[(rp * 8 + cp) * 256 + t];
        tbl[t] = lu | (lb << 8) | (ru << 16) | (rb << 24);
    }
    __syncthreads();

    const size_t ibase = (size_t)b * 1048576;
    const int row_in = t >> 4;
    const int col4   = (t & 15) * 4;

    for (int it = 0; it < 4; ++it) {
        const int i = i0 + it * 16 + row_in;
        const int j = j0 + col4;

        int vv[4];
        if (U8) {
            uchar4 px = *(const uchar4*)(img8 + ibase + (size_t)i * 1024 + j);
            vv[0] = px.x; vv[1] = px.y; vv[2] = px.z; vv[3] = px.w;
        } else {
            float4 px = *(const float4*)(imgf + ibase + (size_t)i * 1024 + j);
            vv[0] = (int)px.x; vv[1] = (int)px.y; vv[2] = (int)px.z; vv[3] = (int)px.w;
        }

        const float x1 = rEdge ? 0.0f : ((float)i - (float)(r * 128 + 64)) * 0.0078125f;
        const float x0 = 1.0f - x1;

        float4 o4;
        float* ov = (float*)&o4;
        for (int k = 0; k < 4; ++k) {
            const int jj = j + k;
            const float y1 = cEdge ? 0.0f : ((float)jj - (float)(c * 128 + 64)) * 0.0078125f;
            unsigned mv = tbl[vv[k]];
            float lu = (float)(mv & 255u);
            float lb = (float)((mv >> 8) & 255u);
            float ru = (float)((mv >> 16) & 255u);
            float rb = (float)(mv >> 24);
            float o = (1.0f - y1) * (x0 * lu + x1 * lb)
                    + y1 * (x0 * ru + x1 * rb);
            ov[k] = (float)(((int)o) & 255);
        }
        *(float4*)(out + ibase + (size_t)i * 1024 + j) = o4;
    }
}

extern "C" void kernel_launch(void* const* d_in, const int* in_sizes, int n_in,
                              void* d_out, int out_size, void* d_ws, size_t ws_size,
                              hipStream_t stream) {
    const float* img = (const float*)d_in[0];
    float* out  = (float*)d_out;
    float* maps = (float*)d_ws;   // 1 MB: 16*64*256 floats

    void* args[] = { (void*)&img, (void*)&out, (void*)&maps };
    hipError_t err = hipLaunchCooperativeKernel((const void*)clahe_fused,
                                                dim3(512), dim3(256), args, 0, stream);
    if (err != hipSuccess) {
        // Deterministic fallback: two-kernel path (bit-exact, round-2 proven).
        const size_t maps_bytes = (size_t)1024 * 256 * sizeof(float);
        const size_t u8_bytes   = (size_t)16 * 1024 * 1024;
        const bool use_u8 = ws_size >= maps_bytes + u8_bytes;
        unsigned char* u8img = use_u8 ? ((unsigned char*)d_ws + maps_bytes) : nullptr;

        clahe_hist_kernel<<<dim3(1024), dim3(256), 0, stream>>>(img, maps, u8img);
        if (use_u8) {
            clahe_map_kernel<true><<<dim3(16, 16, 16), dim3(256), 0, stream>>>(
                nullptr, u8img, maps, out);
        } else {
            clahe_map_kernel<false><<<dim3(16, 16, 16), dim3(256), 0, stream>>>(
                img, nullptr, maps, out);
        }
    }
}

// Round 5
// 125.310 us; speedup vs baseline: 1.9090x; 1.9090x over previous
//
#include <hip/hip_runtime.h>
#include <hip/hip_bf16.h>

#define LEVEL 256
#define BLOCKS 8
// B=16, H=W=1024, bm=bn=128, tv = 16384/256*10 = 640

// ---------------------------------------------------------------------------
// Kernel 1: per-image-block histogram -> clip -> cdf -> map table.
// Per-wave privatized histograms (4 x 256 int, 4 KB LDS) kill inter-wave
// LDS-atomic contention; combined at the end (integer -> exact).
// Also stages pixels as uint8 so kernel 2 reads 16 MB instead of 64 MB.
// grid = 1024, 256 threads.  maps layout: float maps[16][8][8][256]
// ---------------------------------------------------------------------------
__global__ __launch_bounds__(256) void clahe_hist_kernel(const float* __restrict__ img,
                                                         float* __restrict__ maps,
                                                         unsigned char* __restrict__ u8img) {
    __shared__ int   hist[4][256];
    __shared__ float red[256];
    __shared__ float scan[256];
    __shared__ float s_me;

    const int t    = threadIdx.x;
    const int wave = t >> 6;               // 0..3
    const int bid  = blockIdx.x;           // 0..1023
    const int b    = bid >> 6;             // image
    const int blk  = bid & 63;
    const int br   = blk >> 3;
    const int bc   = blk & 7;

    hist[0][t] = 0; hist[1][t] = 0; hist[2][t] = 0; hist[3][t] = 0;
    __syncthreads();

    // 128x128 block = 4096 float4 loads, 16 per thread, coalesced
    const size_t base = (size_t)b * 1048576 + (size_t)(br * 128) * 1024 + (size_t)(bc * 128);
    const float* p = img + base;
    unsigned char* q8 = u8img + base;
    int* myhist = hist[wave];
#pragma unroll
    for (int it = 0; it < 16; ++it) {
        int idx = it * 256 + t;            // 0..4095
        int y   = idx >> 5;                // 0..127
        int x   = (idx & 31) * 4;          // 0..124
        // floats never re-read (u8 staged) -> non-temporal
        const float* src = p + (size_t)y * 1024 + x;
        float4 v;
        v.x = __builtin_nontemporal_load(src + 0);
        v.y = __builtin_nontemporal_load(src + 1);
        v.z = __builtin_nontemporal_load(src + 2);
        v.w = __builtin_nontemporal_load(src + 3);
        int va = (int)v.x, vb = (int)v.y, vc = (int)v.z, vd = (int)v.w;
        atomicAdd(&myhist[va], 1);
        atomicAdd(&myhist[vb], 1);
        atomicAdd(&myhist[vc], 1);
        atomicAdd(&myhist[vd], 1);
        uchar4 pk;
        pk.x = (unsigned char)va; pk.y = (unsigned char)vb;
        pk.z = (unsigned char)vc; pk.w = (unsigned char)vd;
        *(uchar4*)(q8 + (size_t)y * 1024 + x) = pk;
    }
    __syncthreads();

    // combine per-wave histograms (integer-exact)
    float h = (float)(hist[0][t] + hist[1][t] + hist[2][t] + hist[3][t]);

    // clip: tv=640, redistribute excess uniformly (integer-exact in fp32)
    const float tv = 640.0f;
    red[t] = fmaxf(h - tv, 0.0f);
    __syncthreads();
    for (int off = 128; off > 0; off >>= 1) {
        if (t < off) red[t] += red[t + off];
        __syncthreads();
    }
    if (t == 0) s_me = red[0] * (1.0f / 256.0f);   // exact /2^8
    __syncthreads();
    const float me = s_me;
    float clip = floorf(((h >= tv) ? tv : h) + me);

    // inclusive scan over 256 bins (integer-valued -> exact any order)
    scan[t] = clip;
    __syncthreads();
    for (int off = 1; off < 256; off <<= 1) {
        float add = (t >= off) ? scan[t - off] : 0.0f;
        __syncthreads();
        scan[t] += add;
        __syncthreads();
    }
    float cdf = scan[t] * (255.0f / 16384.0f);     // exact 255/2^14
    maps[(size_t)bid * 256 + t] = (float)(((int)floorf(cdf)) & 255);
}

// ---------------------------------------------------------------------------
// Kernel 2: per-pixel bilinear blend. 64x64 tile per workgroup (r,c constant
// inside a 64-aligned tile). 4 corner maps packed u8x4 in one u32 ->
// single random-bank ds_read_b32 per pixel (~2-way conflicts = free).
// Reads the staged u8 image (16 MB); writes out non-temporally (64 MB).
// grid = (16,16,16), 256 threads.
// ---------------------------------------------------------------------------
__global__ __launch_bounds__(256) void clahe_map_kernel(const unsigned char* __restrict__ img8,
                                                        const float* __restrict__ maps,
                                                        float* __restrict__ out) {
#pragma clang fp contract(off)
    __shared__ unsigned int tbl[256];   // packed {lu,lb,ru,rb}

    const int t  = threadIdx.x;
    const int b  = blockIdx.z;
    const int i0 = blockIdx.y * 64;
    const int j0 = blockIdx.x * 64;

    // r = trunc((i-64)/128), constant over the tile
    const int r  = (i0 >= 64) ? ((i0 - 64) >> 7) : 0;
    const int c  = (j0 >= 64) ? ((j0 - 64) >> 7) : 0;
    const int rp = min(r + 1, BLOCKS - 1);
    const int cp = min(c + 1, BLOCKS - 1);
    const bool rEdge = (r >= BLOCKS - 1);
    const bool cEdge = (c >= BLOCKS - 1);

    const float* mb = maps + (size_t)b * 64 * 256;
    {
        unsigned lu = (unsigned)(int)mb[(r  * 8 + c ) * 256 + t];
        unsigned lb = (unsigned)(int)mb[(rp * 8 + c ) * 256 + t];
        unsigned ru = (unsigned)(int)mb[(r  * 8 + cp) * 256 + t];
        unsigned rb = (unsigned)(int)mb[(rp * 8 + cp) * 256 + t];
        tbl[t] = lu | (lb << 8) | (ru << 16) | (rb << 24);
    }
    __syncthreads();

    const size_t ibase = (size_t)b * 1048576;
    const int row_in = t >> 4;          // 0..15
    const int col4   = (t & 15) * 4;    // 0..60

#pragma unroll
    for (int it = 0; it < 4; ++it) {
        const int i = i0 + it * 16 + row_in;
        const int j = j0 + col4;

        uchar4 px = *(const uchar4*)(img8 + ibase + (size_t)i * 1024 + j);
        int vv[4] = { px.x, px.y, px.z, px.w };

        const float x1 = rEdge ? 0.0f : ((float)i - (float)(r * 128 + 64)) * 0.0078125f;
        const float x0 = 1.0f - x1;

        float4 o4;
        float* ov = (float*)&o4;
#pragma unroll
        for (int k = 0; k < 4; ++k) {
            const int jj = j + k;
            const float y1 = cEdge ? 0.0f : ((float)jj - (float)(c * 128 + 64)) * 0.0078125f;
            unsigned mv = tbl[vv[k]];
            float lu = (float)(mv & 255u);
            float lb = (float)((mv >> 8) & 255u);
            float ru = (float)((mv >> 16) & 255u);
            float rb = (float)(mv >> 24);
            // exact expression order of the reference; no FMA contraction
            float o = (1.0f - y1) * (x0 * lu + x1 * lb)
                    + y1 * (x0 * ru + x1 * rb);
            ov[k] = (float)(((int)o) & 255);   // trunc then floor-mod 256
        }
        // out never re-read on device -> non-temporal store
        float* dst = out + ibase + (size_t)i * 1024 + j;
        __builtin_nontemporal_store(o4.x, dst + 0);
        __builtin_nontemporal_store(o4.y, dst + 1);
        __builtin_nontemporal_store(o4.z, dst + 2);
        __builtin_nontemporal_store(o4.w, dst + 3);
    }
}

extern "C" void kernel_launch(void* const* d_in, const int* in_sizes, int n_in,
                              void* d_out, int out_size, void* d_ws, size_t ws_size,
                              hipStream_t stream) {
    const float* img = (const float*)d_in[0];
    float* out  = (float*)d_out;
    float* maps = (float*)d_ws;                      // 1 MB
    unsigned char* u8img = (unsigned char*)d_ws + (size_t)1024 * 256 * sizeof(float); // 16 MB

    clahe_hist_kernel<<<dim3(1024), dim3(256), 0, stream>>>(img, maps, u8img);
    clahe_map_kernel<<<dim3(16, 16, 16), dim3(256), 0, stream>>>(u8img, maps, out);
}